// Round 1
// baseline (434.285 us; speedup 1.0000x reference)
//
#include <hip/hip_runtime.h>
#include <math.h>

// SpectralConvND: rfft2 -> 32x32 mode mixing -> irfft2, decomposed into
// truncated DFT matmuls (only 32x32 modes are ever used/written).
//
// Shapes: x(16,32,256,256) f32; coeff_{real,imag}(32r,32c,32i,32j); proj(32o,32r)
// out(16,32,256,256) f32.

#define NB 16
#define NC 32   // in channels
#define NO 32   // out channels
#define NR 32
#define NH 256
#define NW 256
#define NI 32   // modes along H
#define NJ 32   // modes along W

__constant__ float kTwoPiOver256 = 6.283185307179586476925f / 256.0f;

// ---------------- Wt[o,c,i,j] = sum_r proj[o,r] * (cr + i*ci)[r,c,i,j] -------
__global__ void kW(const float* __restrict__ proj, const float* __restrict__ cr,
                   const float* __restrict__ ci, float2* __restrict__ Wt) {
    __shared__ float2 co[32][33];  // coeff[r][j] for fixed (c,i)
    __shared__ float pr[32 * 32];  // proj[o][r]
    int c = blockIdx.x >> 5;
    int i = blockIdx.x & 31;
    int tid = threadIdx.x;
    for (int idx = tid; idx < 1024; idx += 256) pr[idx] = proj[idx];
    for (int idx = tid; idx < 1024; idx += 256) {
        int r = idx >> 5, j = idx & 31;
        int g = ((r * 32 + c) * 32 + i) * 32 + j;
        co[r][j] = make_float2(cr[g], ci[g]);
    }
    __syncthreads();
    int j = tid & 31, og = tid >> 5;
    for (int oo = 0; oo < 4; ++oo) {
        int o = og * 4 + oo;
        float wr = 0.f, wi = 0.f;
        #pragma unroll
        for (int r = 0; r < 32; ++r) {
            float p = pr[o * 32 + r];
            float2 v = co[r][j];
            wr += p * v.x;
            wi += p * v.y;
        }
        Wt[((o * 32 + c) * 32 + i) * 32 + j] = make_float2(wr, wi);
    }
}

// ---------------- K1: Y1[b,c,j,h] = sum_w x[b,c,h,w] e^{-2pi i j w/256} ------
__global__ void k1(const float* __restrict__ x, float2* __restrict__ Y1) {
    __shared__ float xs[64][257];   // padded: bank = (h*257+w)%32 varies with h
    __shared__ float2 tw[256];
    int bid = blockIdx.x;           // b*128 + c*4 + ht
    int ht = bid & 3, c = (bid >> 2) & 31, b = bid >> 7;
    int tid = threadIdx.x;
    {
        float s, cc;
        sincosf(tid * kTwoPiOver256, &s, &cc);
        tw[tid] = make_float2(cc, s);
    }
    const float* xp = x + (((size_t)(b * 32 + c)) * 256 + ht * 64) * 256;
    for (int idx = tid; idx < 64 * 256; idx += 256)
        xs[idx >> 8][idx & 255] = xp[idx];
    __syncthreads();
    int h = tid & 63, jg = tid >> 6;    // one wave = one jg (64 h lanes)
    float ar[8], ai[8];
    #pragma unroll
    for (int jj = 0; jj < 8; ++jj) { ar[jj] = 0.f; ai[jj] = 0.f; }
    for (int w = 0; w < 256; ++w) {
        float xv = xs[h][w];
        #pragma unroll
        for (int jj = 0; jj < 8; ++jj) {
            int j = jg * 8 + jj;
            float2 t = tw[(j * w) & 255];  // broadcast within wave
            ar[jj] += xv * t.x;            // e^{-i th}: (cos, -sin)
            ai[jj] -= xv * t.y;
        }
    }
    int hg = ht * 64 + h;
    #pragma unroll
    for (int jj = 0; jj < 8; ++jj) {
        int j = jg * 8 + jj;
        Y1[((b * 32 + c) * 32 + j) * 256 + hg] = make_float2(ar[jj], ai[jj]);
    }
}

// ---------------- K2: Xf[b,c,i,j] = sum_h Y1[b,c,j,h] e^{-2pi i i h/256} -----
__global__ void k2(const float2* __restrict__ Y1, float2* __restrict__ Xf) {
    __shared__ float2 ys[32][257];  // [j][h] padded
    __shared__ float2 tw[256];
    int bid = blockIdx.x;           // b*32 + c
    int tid = threadIdx.x;
    {
        float s, cc;
        sincosf(tid * kTwoPiOver256, &s, &cc);
        tw[tid] = make_float2(cc, s);
    }
    const float2* yp = Y1 + (size_t)bid * 32 * 256;
    for (int idx = tid; idx < 32 * 256; idx += 256)
        ys[idx >> 8][idx & 255] = yp[idx];
    __syncthreads();
    int j = tid & 31, ig = tid >> 5;
    for (int ii = 0; ii < 4; ++ii) {
        int i = ig * 4 + ii;
        float xr = 0.f, xi = 0.f;
        for (int h = 0; h < 256; ++h) {
            float2 yv = ys[j][h];
            float2 t = tw[(i * h) & 255];
            // (a+ib)(cos - i sin) = (a c + b s) + i(b c - a s)
            xr += yv.x * t.x + yv.y * t.y;
            xi += yv.y * t.x - yv.x * t.y;
        }
        Xf[(bid * 32 + i) * 32 + j] = make_float2(xr, xi);
    }
}

// ---------------- K3: Of[b,o,i,j] = sum_c Xf[b,c,i,j] * Wt[o,c,i,j] ----------
__global__ void k3(const float2* __restrict__ Xf, const float2* __restrict__ Wt,
                   float2* __restrict__ Of) {
    __shared__ float2 xs[32][33];  // [c][j]
    int bid = blockIdx.x;          // b*32 + i
    int i = bid & 31, b = bid >> 5;
    int tid = threadIdx.x;
    for (int idx = tid; idx < 1024; idx += 256) {
        int c = idx >> 5, j = idx & 31;
        xs[c][j] = Xf[((b * 32 + c) * 32 + i) * 32 + j];
    }
    __syncthreads();
    int j = tid & 31, og = tid >> 5;
    for (int oo = 0; oo < 4; ++oo) {
        int o = og * 4 + oo;
        float orr = 0.f, oi = 0.f;
        for (int c = 0; c < 32; ++c) {
            float2 xv = xs[c][j];
            float2 wv = Wt[((o * 32 + c) * 32 + i) * 32 + j];
            orr += xv.x * wv.x - xv.y * wv.y;
            oi  += xv.x * wv.y + xv.y * wv.x;
        }
        Of[((b * 32 + o) * 32 + i) * 32 + j] = make_float2(orr, oi);
    }
}

// ---------------- K4: T[b,o,i,w] = sum_j cj*Of[i,j] e^{+2pi i j w/256} -------
__global__ void k4(const float2* __restrict__ Of, float2* __restrict__ T) {
    __shared__ float2 os[32][33];  // [i][j], pre-scaled by cj/65536
    __shared__ float2 tw[256];
    int bid = blockIdx.x;          // b*32 + o
    int tid = threadIdx.x;
    {
        float s, cc;
        sincosf(tid * kTwoPiOver256, &s, &cc);
        tw[tid] = make_float2(cc, s);
    }
    for (int idx = tid; idx < 1024; idx += 256) {
        int i = idx >> 5, j = idx & 31;
        float2 v = Of[(size_t)bid * 1024 + idx];
        float sc = (j == 0 ? 1.0f : 2.0f) * (1.0f / 65536.0f);
        os[i][j] = make_float2(v.x * sc, v.y * sc);
    }
    __syncthreads();
    int w = tid;
    for (int i = 0; i < 32; ++i) {
        float tr = 0.f, ti = 0.f;
        #pragma unroll
        for (int jj = 0; jj < 32; ++jj) {
            float2 ov = os[i][jj];             // broadcast across lanes
            float2 t = tw[(jj * w) & 255];
            // (Or+iOi)(cos + i sin)
            tr += ov.x * t.x - ov.y * t.y;
            ti += ov.x * t.y + ov.y * t.x;
        }
        T[((size_t)bid * 32 + i) * 256 + w] = make_float2(tr, ti);
    }
}

// ---------------- K5: out[b,o,h,w] = Re sum_i T[i,w] e^{+2pi i i h/256} ------
__global__ void k5(const float2* __restrict__ T, float* __restrict__ out) {
    __shared__ float2 tw[256];
    int bid = blockIdx.x;          // b*32 + o
    int tid = threadIdx.x;         // = w
    {
        float s, cc;
        sincosf(tid * kTwoPiOver256, &s, &cc);
        tw[tid] = make_float2(cc, s);
    }
    __syncthreads();
    float tr[32], ti[32];
    #pragma unroll
    for (int i = 0; i < 32; ++i) {
        float2 v = T[((size_t)bid * 32 + i) * 256 + tid];
        tr[i] = v.x;
        ti[i] = v.y;
    }
    float* op = out + (size_t)bid * 256 * 256;
    for (int hp = 0; hp < 128; ++hp) {
        float accA = 0.f, accB = 0.f;
        #pragma unroll
        for (int i = 0; i < 32; ++i) {
            float2 t = tw[(i * hp) & 255];     // broadcast across lanes
            float vr = tr[i] * t.x - ti[i] * t.y;
            accA += vr;
            accB += (i & 1) ? -vr : vr;        // h+128: (-1)^i parity
        }
        op[hp * 256 + tid] = accA;
        op[(hp + 128) * 256 + tid] = accB;
    }
}

extern "C" void kernel_launch(void* const* d_in, const int* in_sizes, int n_in,
                              void* d_out, int out_size, void* d_ws, size_t ws_size,
                              hipStream_t stream) {
    const float* x    = (const float*)d_in[0];
    const float* cr   = (const float*)d_in[1];
    const float* ci   = (const float*)d_in[2];
    const float* proj = (const float*)d_in[3];
    float* out = (float*)d_out;
    char* ws = (char*)d_ws;

    const size_t nY  = (size_t)NB * NC * NJ * NH;   // 4,194,304 float2 (33.5 MB)
    const size_t nXf = (size_t)NB * NC * NI * NJ;   //   524,288 float2 ( 4.2 MB)
    const size_t nWt = (size_t)NO * NC * NI * NJ;   // 1,048,576 float2 ( 8.4 MB)

    float2* Y1 = (float2*)ws;                                    // dead after k2
    float2* T  = Y1;                                             // alias (k4+)
    float2* Xf = (float2*)(ws + nY * sizeof(float2));
    float2* Wt = (float2*)(ws + (nY + nXf) * sizeof(float2));
    float2* Of = (float2*)(ws + (nY + nXf + nWt) * sizeof(float2));
    // total ws use: 50,331,648 bytes

    kW<<<1024, 256, 0, stream>>>(proj, cr, ci, Wt);
    k1<<<2048, 256, 0, stream>>>(x, Y1);
    k2<<<512, 256, 0, stream>>>(Y1, Xf);
    k3<<<512, 256, 0, stream>>>(Xf, Wt, Of);
    k4<<<512, 256, 0, stream>>>(Of, T);
    k5<<<512, 256, 0, stream>>>(T, out);
}

// Round 2
// 203.607 us; speedup vs baseline: 2.1330x; 2.1330x over previous
//
#include <hip/hip_runtime.h>
#include <math.h>

// SpectralConvND: rfft2 -> 32x32 mode mixing -> irfft2 as truncated DFT matmuls.
// Round 2: big DFT stages (k1 forward-W, k5 inverse-H) moved to bf16 MFMA.
//
// x(16,32,256,256) f32; coeff(32r,32c,32i,32j) x2; proj(32o,32r); out(16,32,256,256) f32

#define THETA (6.283185307179586f / 256.0f)

typedef float f32x4 __attribute__((ext_vector_type(4)));
typedef __bf16 bf16x8 __attribute__((ext_vector_type(8)));

__device__ __forceinline__ ushort f2bf(float f) {  // RNE fp32 -> bf16 bits
    uint b = __float_as_uint(f);
    b += 0x7FFF + ((b >> 16) & 1);
    return (ushort)(b >> 16);
}

// ---------------- Wt[o,c,i,j] = sum_r proj[o,r] * (cr + i*ci)[r,c,i,j] -------
__global__ void kW(const float* __restrict__ proj, const float* __restrict__ cr,
                   const float* __restrict__ ci, float2* __restrict__ Wt) {
    __shared__ float2 co[32][33];
    __shared__ float pr[32 * 32];
    int c = blockIdx.x >> 5;
    int i = blockIdx.x & 31;
    int tid = threadIdx.x;
    for (int idx = tid; idx < 1024; idx += 256) pr[idx] = proj[idx];
    for (int idx = tid; idx < 1024; idx += 256) {
        int r = idx >> 5, j = idx & 31;
        int g = ((r * 32 + c) * 32 + i) * 32 + j;
        co[r][j] = make_float2(cr[g], ci[g]);
    }
    __syncthreads();
    int j = tid & 31, og = tid >> 5;
    for (int oo = 0; oo < 4; ++oo) {
        int o = og * 4 + oo;
        float wr = 0.f, wi = 0.f;
        #pragma unroll
        for (int r = 0; r < 32; ++r) {
            float p = pr[o * 32 + r];
            float2 v = co[r][j];
            wr += p * v.x;
            wi += p * v.y;
        }
        Wt[((o * 32 + c) * 32 + i) * 32 + j] = make_float2(wr, wi);
    }
}

// ---- K1 (MFMA): Y1[jr,h] = sum_w D[jr,w] x[h,w] per (b,c); planar f32 out ---
// D[2j][w]=cos(2pi jw/256), D[2j+1][w]=-sin(2pi jw/256), bf16.
__global__ void __launch_bounds__(256) k1(const float* __restrict__ x,
                                          float* __restrict__ Y1r,
                                          float* __restrict__ Y1i) {
    __shared__ ushort Dl[64 * 136];    // per-half D tile, stride 136 (16B-odd)
    __shared__ ushort Xl[128 * 136];   // per-half x tile (bf16)
    int bid = blockIdx.x;              // bc*2 + hh
    int hh = bid & 1, bc = bid >> 1;
    int tid = threadIdx.x;
    int l = tid & 63, wv = tid >> 6;
    int lr = l & 15, kg = l >> 4;

    f32x4 acc[4][2];
    #pragma unroll
    for (int mt = 0; mt < 4; ++mt)
        #pragma unroll
        for (int nt = 0; nt < 2; ++nt)
            acc[mt][nt] = (f32x4){0.f, 0.f, 0.f, 0.f};

    const float4* xp4 = (const float4*)(x + ((size_t)bc * 256 + hh * 128) * 256);

    for (int half = 0; half < 2; ++half) {
        if (half) __syncthreads();     // previous compute done before LDS reuse
        // build D tile for this w-half: 8192 entries
        for (int k = 0; k < 32; ++k) {
            int idx = tid + 256 * k;
            int jr = idx >> 7, wl = idx & 127;
            int j = jr >> 1, w = half * 128 + wl;
            float s, c;
            __sincosf(((j * w) & 255) * THETA, &s, &c);
            Dl[jr * 136 + wl] = f2bf((jr & 1) ? -s : c);
        }
        // stage x half-tile: 128 rows x 128 w, fp32 -> bf16
        #pragma unroll
        for (int k = 0; k < 16; ++k) {
            int idx = tid + 256 * k;
            int row = idx >> 5, wl4 = idx & 31;
            float4 v = xp4[row * 64 + half * 32 + wl4];
            ushort4 u = make_ushort4(f2bf(v.x), f2bf(v.y), f2bf(v.z), f2bf(v.w));
            *(ushort4*)&Xl[row * 136 + wl4 * 4] = u;
        }
        __syncthreads();
        #pragma unroll
        for (int ks = 0; ks < 4; ++ks) {
            bf16x8 a[4], b[2];
            #pragma unroll
            for (int mt = 0; mt < 4; ++mt)
                a[mt] = *(const bf16x8*)&Dl[(mt * 16 + lr) * 136 + ks * 32 + kg * 8];
            #pragma unroll
            for (int nt = 0; nt < 2; ++nt)
                b[nt] = *(const bf16x8*)&Xl[((wv * 2 + nt) * 16 + lr) * 136 + ks * 32 + kg * 8];
            #pragma unroll
            for (int mt = 0; mt < 4; ++mt)
                #pragma unroll
                for (int nt = 0; nt < 2; ++nt)
                    acc[mt][nt] = __builtin_amdgcn_mfma_f32_16x16x32_bf16(
                        a[mt], b[nt], acc[mt][nt], 0, 0, 0);
        }
    }
    // store: C/D map col=lane&15, row=(lane>>4)*4+reg; jr parity == reg parity
    #pragma unroll
    for (int mt = 0; mt < 4; ++mt)
        #pragma unroll
        for (int nt = 0; nt < 2; ++nt)
            #pragma unroll
            for (int r = 0; r < 4; ++r) {
                int jr = mt * 16 + kg * 4 + r;
                int j = jr >> 1;
                int h = hh * 128 + (wv * 2 + nt) * 16 + lr;
                float* plane = (jr & 1) ? Y1i : Y1r;
                plane[((size_t)bc * 32 + j) * 256 + h] = acc[mt][nt][r];
            }
}

// ---------------- K2: Xf[b,c,i,j] = sum_h Y1[b,c,j,h] e^{-2pi i i h/256} -----
__global__ void k2(const float* __restrict__ Y1r, const float* __restrict__ Y1i,
                   float2* __restrict__ Xf) {
    __shared__ float2 ys[32][257];  // [j][h] padded
    __shared__ float2 tw[256];
    int bid = blockIdx.x;           // b*32 + c
    int tid = threadIdx.x;
    {
        float s, cc;
        sincosf(tid * THETA, &s, &cc);
        tw[tid] = make_float2(cc, s);
    }
    const float* yr = Y1r + (size_t)bid * 8192;
    const float* yi = Y1i + (size_t)bid * 8192;
    for (int idx = tid; idx < 8192; idx += 256)
        ys[idx >> 8][idx & 255] = make_float2(yr[idx], yi[idx]);
    __syncthreads();
    int j = tid & 31, ig = tid >> 5;
    for (int ii = 0; ii < 4; ++ii) {
        int i = ig * 4 + ii;
        float xr = 0.f, xi = 0.f;
        for (int h = 0; h < 256; ++h) {
            float2 yv = ys[j][h];
            float2 t = tw[(i * h) & 255];
            xr += yv.x * t.x + yv.y * t.y;
            xi += yv.y * t.x - yv.x * t.y;
        }
        Xf[(bid * 32 + i) * 32 + j] = make_float2(xr, xi);
    }
}

// ---------------- K3: Of[b,o,i,j] = sum_c Xf[b,c,i,j] * Wt[o,c,i,j] ----------
__global__ void k3(const float2* __restrict__ Xf, const float2* __restrict__ Wt,
                   float2* __restrict__ Of) {
    __shared__ float2 xs[32][33];  // [c][j]
    int bid = blockIdx.x;          // b*32 + i
    int i = bid & 31, b = bid >> 5;
    int tid = threadIdx.x;
    for (int idx = tid; idx < 1024; idx += 256) {
        int c = idx >> 5, j = idx & 31;
        xs[c][j] = Xf[((b * 32 + c) * 32 + i) * 32 + j];
    }
    __syncthreads();
    int j = tid & 31, og = tid >> 5;
    for (int oo = 0; oo < 4; ++oo) {
        int o = og * 4 + oo;
        float orr = 0.f, oi = 0.f;
        for (int c = 0; c < 32; ++c) {
            float2 xv = xs[c][j];
            float2 wv = Wt[((o * 32 + c) * 32 + i) * 32 + j];
            orr += xv.x * wv.x - xv.y * wv.y;
            oi  += xv.x * wv.y + xv.y * wv.x;
        }
        Of[((b * 32 + o) * 32 + i) * 32 + j] = make_float2(orr, oi);
    }
}

// ---- K4: T2t[w][kr] bf16 = (Tr,Ti interleaved), T[i,w]=sum_j cj*Of e^{+..} --
__global__ void __launch_bounds__(256) k4(const float2* __restrict__ Of,
                                          uint* __restrict__ T2u) {
    __shared__ float2 os[32][33];  // [i][j], pre-scaled by cj/65536
    __shared__ float2 tw[256];
    int bid = blockIdx.x;          // b*32 + o
    int tid = threadIdx.x;
    {
        float s, cc;
        sincosf(tid * THETA, &s, &cc);
        tw[tid] = make_float2(cc, s);
    }
    for (int idx = tid; idx < 1024; idx += 256) {
        int i = idx >> 5, j = idx & 31;
        float2 v = Of[(size_t)bid * 1024 + idx];
        float sc = (j == 0 ? 1.0f : 2.0f) * (1.0f / 65536.0f);
        os[i][j] = make_float2(v.x * sc, v.y * sc);
    }
    __syncthreads();
    int w = tid;
    float tr[32], ti[32];
    #pragma unroll
    for (int i = 0; i < 32; ++i) { tr[i] = 0.f; ti[i] = 0.f; }
    for (int jj = 0; jj < 32; ++jj) {
        float2 t = tw[(jj * w) & 255];       // hoisted: shared by all i
        #pragma unroll
        for (int i = 0; i < 32; ++i) {
            float2 ov = os[i][jj];           // lane-uniform broadcast
            tr[i] += ov.x * t.x - ov.y * t.y;
            ti[i] += ov.x * t.y + ov.y * t.x;
        }
    }
    uint pk[32];
    #pragma unroll
    for (int i = 0; i < 32; ++i)
        pk[i] = (uint)f2bf(tr[i]) | ((uint)f2bf(ti[i]) << 16);
    uint* dst = T2u + (size_t)bid * 8192 + w * 32;   // [w][32 pairs] 128B/thread
    #pragma unroll
    for (int q = 0; q < 8; ++q)
        *(uint4*)(dst + q * 4) = make_uint4(pk[4*q], pk[4*q+1], pk[4*q+2], pk[4*q+3]);
}

// ---- K5 (MFMA): out[h,w] = sum_kr E[h,kr] T2t[w,kr] per (b,o,w-quarter) -----
// E[h][2i]=cos(2pi ih/256), E[h][2i+1]=-sin(2pi ih/256), bf16.
__global__ void __launch_bounds__(256) k5(const ushort* __restrict__ T2t,
                                          float* __restrict__ out) {
    __shared__ ushort El[256 * 72];   // stride 72 (16B-odd)
    __shared__ ushort Tl[64 * 72];
    int bid = blockIdx.x;             // bo*4 + wq
    int wq = bid & 3, bo = bid >> 2;
    int tid = threadIdx.x;
    int l = tid & 63, wv = tid >> 6;
    int lr = l & 15, kg = l >> 4;
    {   // E row h = tid
        int h = tid;
        #pragma unroll
        for (int i = 0; i < 32; ++i) {
            float s, c;
            __sincosf(((i * h) & 255) * THETA, &s, &c);
            El[h * 72 + 2 * i]     = f2bf(c);
            El[h * 72 + 2 * i + 1] = f2bf(-s);
        }
    }
    {   // stage T2t tile: 64 w-rows x 64 kr
        const uint* srcu = (const uint*)(T2t + ((size_t)bo * 256 + wq * 64) * 64);
        #pragma unroll
        for (int k = 0; k < 2; ++k) {
            int idx = tid + 256 * k;
            int row = idx >> 3, c8 = idx & 7;
            uint4 v = *(const uint4*)(srcu + row * 32 + c8 * 4);
            *(uint4*)&Tl[row * 72 + c8 * 8] = v;
        }
    }
    __syncthreads();
    f32x4 acc[4][4];
    #pragma unroll
    for (int mm = 0; mm < 4; ++mm)
        #pragma unroll
        for (int nt = 0; nt < 4; ++nt)
            acc[mm][nt] = (f32x4){0.f, 0.f, 0.f, 0.f};
    #pragma unroll
    for (int ks = 0; ks < 2; ++ks) {
        bf16x8 a[4], b[4];
        #pragma unroll
        for (int mm = 0; mm < 4; ++mm)
            a[mm] = *(const bf16x8*)&El[((wv * 4 + mm) * 16 + lr) * 72 + ks * 32 + kg * 8];
        #pragma unroll
        for (int nt = 0; nt < 4; ++nt)
            b[nt] = *(const bf16x8*)&Tl[(nt * 16 + lr) * 72 + ks * 32 + kg * 8];
        #pragma unroll
        for (int mm = 0; mm < 4; ++mm)
            #pragma unroll
            for (int nt = 0; nt < 4; ++nt)
                acc[mm][nt] = __builtin_amdgcn_mfma_f32_16x16x32_bf16(
                    a[mm], b[nt], acc[mm][nt], 0, 0, 0);
    }
    float* op = out + (size_t)bo * 65536 + wq * 64;
    #pragma unroll
    for (int mm = 0; mm < 4; ++mm)
        #pragma unroll
        for (int nt = 0; nt < 4; ++nt)
            #pragma unroll
            for (int r = 0; r < 4; ++r) {
                int h = (wv * 4 + mm) * 16 + kg * 4 + r;
                int w = nt * 16 + lr;
                op[h * 256 + w] = acc[mm][nt][r];
            }
}

extern "C" void kernel_launch(void* const* d_in, const int* in_sizes, int n_in,
                              void* d_out, int out_size, void* d_ws, size_t ws_size,
                              hipStream_t stream) {
    const float* x    = (const float*)d_in[0];
    const float* cr   = (const float*)d_in[1];
    const float* ci   = (const float*)d_in[2];
    const float* proj = (const float*)d_in[3];
    float* out = (float*)d_out;
    char* ws = (char*)d_ws;

    // ws layout (50,331,648 B total):
    //   Y1r  @ 0         16,777,216 B   (512 bc x 32 j x 256 h f32)
    //   Y1i  @ 16MiB     16,777,216 B
    //   Xf   @ 32MiB      4,194,304 B   (float2)
    //   Wt   @ 36MiB      8,388,608 B   (float2)
    //   Of   @ 44MiB      4,194,304 B   (float2)
    //   T2t  @ 0 (alias) 16,777,216 B   (512 bo x 256 w x 64 kr bf16) - Y1 dead by k4
    float*  Y1r = (float*)ws;
    float*  Y1i = (float*)(ws + 16777216);
    float2* Xf  = (float2*)(ws + 33554432);
    float2* Wt  = (float2*)(ws + 37748736);
    float2* Of  = (float2*)(ws + 46137344);
    uint*   T2u = (uint*)ws;

    kW<<<1024, 256, 0, stream>>>(proj, cr, ci, Wt);
    k1<<<1024, 256, 0, stream>>>(x, Y1r, Y1i);
    k2<<<512, 256, 0, stream>>>(Y1r, Y1i, Xf);
    k3<<<512, 256, 0, stream>>>(Xf, Wt, Of);
    k4<<<512, 256, 0, stream>>>(Of, T2u);
    k5<<<2048, 256, 0, stream>>>((const ushort*)T2u, out);
}

// Round 4
// 137.583 us; speedup vs baseline: 3.1565x; 1.4799x over previous
//
#include <hip/hip_runtime.h>
#include <math.h>

// SpectralConvND: rfft2 -> 32x32 mode mixing -> irfft2 as truncated DFT matmuls.
// Round 4: fix R3's two bugs: (1) k2 LDS tile stride 136 -> 264 (rows are 256
// wide; old code overlapped rows + OOB); (2) k4's misaligned LDS-transpose
// uint4 reads -> direct uint2 global stores (no LDS transpose).
//
// x(16,32,256,256) f32; coeff(32r,32c,32i,32j) x2; proj(32o,32r); out(16,32,256,256) f32

#define THETA (6.283185307179586f / 256.0f)

typedef float f32x4 __attribute__((ext_vector_type(4)));
typedef __bf16 bf16x8 __attribute__((ext_vector_type(8)));

__device__ __forceinline__ ushort f2bf(float f) {  // RNE fp32 -> bf16 bits
    uint b = __float_as_uint(f);
    b += 0x7FFF + ((b >> 16) & 1);
    return (ushort)(b >> 16);
}

// ---- kTw: twiddle tables ----------------------------------------------------
// Dbf[jr][w]  (64x256): jr=2j -> cos(2pi jw/256), jr=2j+1 -> -sin   (fwd DFT rows)
// Gbf[w][kc]  (256x64): kc=2j -> cos(2pi jw/256), kc=2j+1 -> +sin   (inv-W, B side)
// Ebf[h][ir]  (256x64): ir=2i -> cos(2pi ih/256), ir=2i+1 -> -sin   (inv-H, A side)
__global__ void kTw(ushort* __restrict__ Dbf, ushort* __restrict__ Gbf,
                    ushort* __restrict__ Ebf) {
    int blk = blockIdx.x, tid = threadIdx.x;
    float s, c;
    if (blk < 64) {
        int jr = blk, w = tid;
        __sincosf((((jr >> 1) * w) & 255) * THETA, &s, &c);
        Dbf[jr * 256 + w] = (jr & 1) ? f2bf(-s) : f2bf(c);
        Gbf[w * 64 + jr]  = (jr & 1) ? f2bf(s)  : f2bf(c);
    } else {
        int e = (blk - 64) * 256 + tid;
        int h = e >> 6, ir = e & 63;
        __sincosf((((ir >> 1) * h) & 255) * THETA, &s, &c);
        Ebf[h * 64 + ir] = (ir & 1) ? f2bf(-s) : f2bf(c);
    }
}

// ---- kW: Wt[o,c,i,j] = sum_r proj[o,r] * (cr + i*ci)[r,c,i,j] ---------------
__global__ void kW(const float* __restrict__ proj, const float* __restrict__ cr,
                   const float* __restrict__ ci, float2* __restrict__ Wt) {
    __shared__ float2 co[32][33];
    __shared__ float pr[32 * 32];
    int c = blockIdx.x >> 5;
    int i = blockIdx.x & 31;
    int tid = threadIdx.x;
    for (int idx = tid; idx < 1024; idx += 256) pr[idx] = proj[idx];
    for (int idx = tid; idx < 1024; idx += 256) {
        int r = idx >> 5, j = idx & 31;
        int g = ((r * 32 + c) * 32 + i) * 32 + j;
        co[r][j] = make_float2(cr[g], ci[g]);
    }
    __syncthreads();
    int j = tid & 31, og = tid >> 5;
    for (int oo = 0; oo < 4; ++oo) {
        int o = og * 4 + oo;
        float wr = 0.f, wi = 0.f;
        #pragma unroll
        for (int r = 0; r < 32; ++r) {
            float p = pr[o * 32 + r];
            float2 v = co[r][j];
            wr += p * v.x;
            wi += p * v.y;
        }
        Wt[((o * 32 + c) * 32 + i) * 32 + j] = make_float2(wr, wi);
    }
}

// ---- K1 (MFMA): Y1[jr,h] = sum_w D[jr,w] x[h,w] per (b,c); bf16 planar out --
__global__ void __launch_bounds__(256) k1(const float* __restrict__ x,
                                          const ushort* __restrict__ Dbf,
                                          ushort* __restrict__ Y1r,
                                          ushort* __restrict__ Y1i) {
    __shared__ __align__(16) ushort Xl[128 * 136];  // x half-tile bf16, 34.8 KB
    int bid = blockIdx.x;              // bc*2 + hh
    int hh = bid & 1, bc = bid >> 1;
    int tid = threadIdx.x;
    int l = tid & 63, wv = tid >> 6;
    int lr = l & 15, kg = l >> 4;

    f32x4 acc[4][2];
    #pragma unroll
    for (int mt = 0; mt < 4; ++mt)
        #pragma unroll
        for (int nt = 0; nt < 2; ++nt)
            acc[mt][nt] = (f32x4){0.f, 0.f, 0.f, 0.f};

    const float4* xp4 = (const float4*)(x + ((size_t)bc * 256 + hh * 128) * 256);

    for (int half = 0; half < 2; ++half) {
        if (half) __syncthreads();
        #pragma unroll
        for (int k = 0; k < 16; ++k) {
            int idx = tid + 256 * k;
            int row = idx >> 5, wl4 = idx & 31;
            float4 v = xp4[row * 64 + half * 32 + wl4];
            ushort4 u = make_ushort4(f2bf(v.x), f2bf(v.y), f2bf(v.z), f2bf(v.w));
            *(ushort4*)&Xl[row * 136 + wl4 * 4] = u;
        }
        __syncthreads();
        #pragma unroll
        for (int ks = 0; ks < 4; ++ks) {
            bf16x8 a[4], b[2];
            #pragma unroll
            for (int mt = 0; mt < 4; ++mt)
                a[mt] = *(const bf16x8*)&Dbf[(mt * 16 + lr) * 256 + half * 128 + ks * 32 + kg * 8];
            #pragma unroll
            for (int nt = 0; nt < 2; ++nt)
                b[nt] = *(const bf16x8*)&Xl[((wv * 2 + nt) * 16 + lr) * 136 + ks * 32 + kg * 8];
            #pragma unroll
            for (int mt = 0; mt < 4; ++mt)
                #pragma unroll
                for (int nt = 0; nt < 2; ++nt)
                    acc[mt][nt] = __builtin_amdgcn_mfma_f32_16x16x32_bf16(
                        a[mt], b[nt], acc[mt][nt], 0, 0, 0);
        }
    }
    #pragma unroll
    for (int mt = 0; mt < 4; ++mt)
        #pragma unroll
        for (int nt = 0; nt < 2; ++nt)
            #pragma unroll
            for (int r = 0; r < 4; ++r) {
                int jr = mt * 16 + kg * 4 + r;
                int j = jr >> 1;
                int h = hh * 128 + (wv * 2 + nt) * 16 + lr;
                ushort* plane = (jr & 1) ? Y1i : Y1r;
                plane[(size_t)bc * 8192 + j * 256 + h] = f2bf(acc[mt][nt][r]);
            }
}

// ---- K2 (MFMA): P = D(64x256) x [Y1r|Y1i]^T -> combine -> Xf[b,c,i,j] -------
// Bl rows are 256 ushorts wide; stride 264 (= 33 x 16B, odd -> conflict-free).
__global__ void __launch_bounds__(256) k2(const ushort* __restrict__ Y1r,
                                          const ushort* __restrict__ Y1i,
                                          const ushort* __restrict__ Dbf,
                                          float2* __restrict__ Xf) {
    __shared__ __align__(16) ushort Bl[64 * 264];  // 33.8 KB; aliased as Ol f32[64*68]
    int bc = blockIdx.x;
    int tid = threadIdx.x;
    int l = tid & 63, wv = tid >> 6;
    int lr = l & 15, kg = l >> 4;

    const uint4* srcR = (const uint4*)(Y1r + (size_t)bc * 8192);
    const uint4* srcI = (const uint4*)(Y1i + (size_t)bc * 8192);
    #pragma unroll
    for (int k = 0; k < 8; ++k) {
        int idx = tid + 256 * k;        // 2048 x 16B
        int row = idx >> 5, c8 = idx & 31;
        uint4 v = (row < 32) ? srcR[row * 32 + c8] : srcI[(row - 32) * 32 + c8];
        *(uint4*)&Bl[row * 264 + c8 * 8] = v;
    }
    __syncthreads();
    f32x4 acc[4];
    #pragma unroll
    for (int mt = 0; mt < 4; ++mt) acc[mt] = (f32x4){0.f, 0.f, 0.f, 0.f};
    #pragma unroll
    for (int ks = 0; ks < 8; ++ks) {
        bf16x8 a[4], b;
        #pragma unroll
        for (int mt = 0; mt < 4; ++mt)
            a[mt] = *(const bf16x8*)&Dbf[(mt * 16 + lr) * 256 + ks * 32 + kg * 8];
        b = *(const bf16x8*)&Bl[(wv * 16 + lr) * 264 + ks * 32 + kg * 8];
        #pragma unroll
        for (int mt = 0; mt < 4; ++mt)
            acc[mt] = __builtin_amdgcn_mfma_f32_16x16x32_bf16(a[mt], b, acc[mt], 0, 0, 0);
    }
    __syncthreads();                     // all B reads done; reuse LDS as Ol
    float* Ol = (float*)Bl;              // [64 m][68 stride]
    #pragma unroll
    for (int mt = 0; mt < 4; ++mt)
        #pragma unroll
        for (int r = 0; r < 4; ++r)
            Ol[(mt * 16 + kg * 4 + r) * 68 + wv * 16 + lr] = acc[mt][r];
    __syncthreads();
    // Xr = P[2i][j] - P[2i+1][32+j]; Xi = P[2i][32+j] + P[2i+1][j]
    #pragma unroll
    for (int q = 0; q < 4; ++q) {
        int idx = tid + 256 * q;
        int i = idx >> 5, j = idx & 31;
        float Xr = Ol[(2 * i) * 68 + j] - Ol[(2 * i + 1) * 68 + 32 + j];
        float Xi = Ol[(2 * i) * 68 + 32 + j] + Ol[(2 * i + 1) * 68 + j];
        Xf[((size_t)bc * 32 + i) * 32 + j] = make_float2(Xr, Xi);
    }
}

// ---- K3: Of[b,o,i,j] = sum_c Xf[b,c,i,j] * Wt[o,c,i,j] ----------------------
__global__ void k3(const float2* __restrict__ Xf, const float2* __restrict__ Wt,
                   float2* __restrict__ Of) {
    __shared__ float2 xs[32][33];  // [c][j]
    int bid = blockIdx.x;          // b*32 + i
    int i = bid & 31, b = bid >> 5;
    int tid = threadIdx.x;
    for (int idx = tid; idx < 1024; idx += 256) {
        int c = idx >> 5, j = idx & 31;
        xs[c][j] = Xf[((b * 32 + c) * 32 + i) * 32 + j];
    }
    __syncthreads();
    int j = tid & 31, og = tid >> 5;
    for (int oo = 0; oo < 4; ++oo) {
        int o = og * 4 + oo;
        float orr = 0.f, oi = 0.f;
        for (int c = 0; c < 32; ++c) {
            float2 xv = xs[c][j];
            float2 wv = Wt[((o * 32 + c) * 32 + i) * 32 + j];
            orr += xv.x * wv.x - xv.y * wv.y;
            oi  += xv.x * wv.y + xv.y * wv.x;
        }
        Of[((b * 32 + o) * 32 + i) * 32 + j] = make_float2(orr, oi);
    }
}

// ---- K4 (MFMA): T2t[w][kr] = A(64kr x 64kc) x Gbf(kc x w), A from Of --------
// Direct global uint2 stores of the C/D fragments (no LDS transpose).
__global__ void __launch_bounds__(256) k4(const float2* __restrict__ Of,
                                          const ushort* __restrict__ Gbf,
                                          uint* __restrict__ T2u) {
    __shared__ __align__(16) ushort Al[64 * 72];    // 9.2 KB
    int bo = blockIdx.x;
    int tid = threadIdx.x;
    int l = tid & 63, wv = tid >> 6;
    int lr = l & 15, kg = l >> 4;
    #pragma unroll
    for (int q = 0; q < 4; ++q) {
        int idx = tid + 256 * q;
        int i = idx >> 5, j = idx & 31;
        float2 v = Of[(size_t)bo * 1024 + idx];
        float sc = (j ? 2.0f : 1.0f) * (1.0f / 65536.0f);
        Al[(2 * i) * 72 + 2 * j]         = f2bf(sc * v.x);
        Al[(2 * i) * 72 + 2 * j + 1]     = f2bf(-sc * v.y);
        Al[(2 * i + 1) * 72 + 2 * j]     = f2bf(sc * v.y);
        Al[(2 * i + 1) * 72 + 2 * j + 1] = f2bf(sc * v.x);
    }
    __syncthreads();
    f32x4 acc[4][4];
    #pragma unroll
    for (int mt = 0; mt < 4; ++mt)
        #pragma unroll
        for (int nt = 0; nt < 4; ++nt)
            acc[mt][nt] = (f32x4){0.f, 0.f, 0.f, 0.f};
    #pragma unroll
    for (int ks = 0; ks < 2; ++ks) {
        bf16x8 a[4], b[4];
        #pragma unroll
        for (int mt = 0; mt < 4; ++mt)
            a[mt] = *(const bf16x8*)&Al[(mt * 16 + lr) * 72 + ks * 32 + kg * 8];
        #pragma unroll
        for (int nt = 0; nt < 4; ++nt)
            b[nt] = *(const bf16x8*)&Gbf[(wv * 64 + nt * 16 + lr) * 64 + ks * 32 + kg * 8];
        #pragma unroll
        for (int mt = 0; mt < 4; ++mt)
            #pragma unroll
            for (int nt = 0; nt < 4; ++nt)
                acc[mt][nt] = __builtin_amdgcn_mfma_f32_16x16x32_bf16(
                    a[mt], b[nt], acc[mt][nt], 0, 0, 0);
    }
    // acc[mt][nt][r]: kr = mt*16 + kg*4 + r (even kr=Tr, odd=Ti), w-col = wv*64+nt*16+lr
    uint* dst = T2u + (size_t)bo * 8192;
    #pragma unroll
    for (int mt = 0; mt < 4; ++mt) {
        int i0 = mt * 8 + kg * 2;       // uint-pair index (i, i+1)
        #pragma unroll
        for (int nt = 0; nt < 4; ++nt) {
            int w = wv * 64 + nt * 16 + lr;
            uint p0 = (uint)f2bf(acc[mt][nt][0]) | ((uint)f2bf(acc[mt][nt][1]) << 16);
            uint p1 = (uint)f2bf(acc[mt][nt][2]) | ((uint)f2bf(acc[mt][nt][3]) << 16);
            *(uint2*)(dst + w * 32 + i0) = make_uint2(p0, p1);
        }
    }
}

// ---- K5 (MFMA): out[h,w] = sum_kr Ebf[h,kr] T2t[w,kr] per (b,o,w-quarter) ---
__global__ void __launch_bounds__(256) k5(const ushort* __restrict__ T2t,
                                          const ushort* __restrict__ Ebf,
                                          float* __restrict__ out) {
    __shared__ __align__(16) ushort Tl[64 * 72];   // 9.2 KB
    int bid = blockIdx.x;             // bo*4 + wq
    int wq = bid & 3, bo = bid >> 2;
    int tid = threadIdx.x;
    int l = tid & 63, wv = tid >> 6;
    int lr = l & 15, kg = l >> 4;
    {
        const uint* srcu = (const uint*)(T2t + ((size_t)bo * 256 + wq * 64) * 64);
        #pragma unroll
        for (int k = 0; k < 2; ++k) {
            int idx = tid + 256 * k;
            int row = idx >> 3, c8 = idx & 7;
            uint4 v = *(const uint4*)(srcu + row * 32 + c8 * 4);
            *(uint4*)&Tl[row * 72 + c8 * 8] = v;
        }
    }
    __syncthreads();
    f32x4 acc[4][4];
    #pragma unroll
    for (int mm = 0; mm < 4; ++mm)
        #pragma unroll
        for (int nt = 0; nt < 4; ++nt)
            acc[mm][nt] = (f32x4){0.f, 0.f, 0.f, 0.f};
    #pragma unroll
    for (int ks = 0; ks < 2; ++ks) {
        bf16x8 a[4], b[4];
        #pragma unroll
        for (int mm = 0; mm < 4; ++mm)
            a[mm] = *(const bf16x8*)&Ebf[((wv * 4 + mm) * 16 + lr) * 64 + ks * 32 + kg * 8];
        #pragma unroll
        for (int nt = 0; nt < 4; ++nt)
            b[nt] = *(const bf16x8*)&Tl[(nt * 16 + lr) * 72 + ks * 32 + kg * 8];
        #pragma unroll
        for (int mm = 0; mm < 4; ++mm)
            #pragma unroll
            for (int nt = 0; nt < 4; ++nt)
                acc[mm][nt] = __builtin_amdgcn_mfma_f32_16x16x32_bf16(
                    a[mm], b[nt], acc[mm][nt], 0, 0, 0);
    }
    float* op = out + (size_t)bo * 65536 + wq * 64;
    #pragma unroll
    for (int mm = 0; mm < 4; ++mm)
        #pragma unroll
        for (int nt = 0; nt < 4; ++nt)
            #pragma unroll
            for (int r = 0; r < 4; ++r) {
                int h = (wv * 4 + mm) * 16 + kg * 4 + r;
                int w = nt * 16 + lr;
                op[h * 256 + w] = acc[mm][nt][r];
            }
}

extern "C" void kernel_launch(void* const* d_in, const int* in_sizes, int n_in,
                              void* d_out, int out_size, void* d_ws, size_t ws_size,
                              hipStream_t stream) {
    const float* x    = (const float*)d_in[0];
    const float* cr   = (const float*)d_in[1];
    const float* ci   = (const float*)d_in[2];
    const float* proj = (const float*)d_in[3];
    float* out = (float*)d_out;
    char* ws = (char*)d_ws;

    // ws layout (33,652,736 B used):
    //   Y1r @ 0         8,388,608  (512 bc x 32 j x 256 h bf16)
    //   Y1i @ 8MiB      8,388,608
    //   Xf  @ 16MiB     4,194,304  (float2)
    //   Wt  @ 20MiB     8,388,608  (float2)
    //   Of  @ 28MiB     4,194,304  (float2)
    //   Dbf @ 32MiB        32,768  (bf16 64x256)
    //   Gbf @ +32KB        32,768  (bf16 256x64)
    //   Ebf @ +64KB        32,768  (bf16 256x64)
    //   T2t @ 0 (alias Y1, dead after k2) 16,777,216 (512 bo x 256 w x 32 uint)
    ushort* Y1r = (ushort*)ws;
    ushort* Y1i = (ushort*)(ws + 8388608);
    float2* Xf  = (float2*)(ws + 16777216);
    float2* Wt  = (float2*)(ws + 20971520);
    float2* Of  = (float2*)(ws + 29360128);
    ushort* Dbf = (ushort*)(ws + 33554432);
    ushort* Gbf = (ushort*)(ws + 33554432 + 32768);
    ushort* Ebf = (ushort*)(ws + 33554432 + 65536);
    uint*   T2u = (uint*)ws;

    kTw<<<128, 256, 0, stream>>>(Dbf, Gbf, Ebf);
    kW<<<1024, 256, 0, stream>>>(proj, cr, ci, Wt);
    k1<<<1024, 256, 0, stream>>>(x, Dbf, Y1r, Y1i);
    k2<<<512, 256, 0, stream>>>(Y1r, Y1i, Dbf, Xf);
    k3<<<512, 256, 0, stream>>>(Xf, Wt, Of);
    k4<<<512, 256, 0, stream>>>(Of, Gbf, T2u);
    k5<<<2048, 256, 0, stream>>>((const ushort*)T2u, Ebf, out);
}

// Round 5
// 100.039 us; speedup vs baseline: 4.3412x; 1.3753x over previous
//
#include <hip/hip_runtime.h>
#include <math.h>

// SpectralConvND: rfft2 -> 32x32 mode mixing -> irfft2 as truncated DFT matmuls.
// Round 5: fusion. kA = k1+k2 (Y1 stays in LDS), kB = k4+k5 (T2 stays in LDS),
// kTw merged into kSetup with kW. 7 kernels -> 4; Y1/T2 HBM round-trips gone.
//
// x(16,32,256,256) f32; coeff(32r,32c,32i,32j) x2; proj(32o,32r); out(16,32,256,256) f32

#define THETA (6.283185307179586f / 256.0f)

typedef float f32x4 __attribute__((ext_vector_type(4)));
typedef __bf16 bf16x8 __attribute__((ext_vector_type(8)));

__device__ __forceinline__ ushort f2bf(float f) {  // RNE fp32 -> bf16 bits
    uint b = __float_as_uint(f);
    b += 0x7FFF + ((b >> 16) & 1);
    return (ushort)(b >> 16);
}

// ---- kSetup: twiddle tables (blocks 0..127) + Wt projection (blocks 128..1151)
// Dbf[jr][w]  (64x256): jr=2j -> cos(2pi jw/256), jr=2j+1 -> -sin   (fwd DFT rows)
// Gbf[w][kc]  (256x64): kc=2j -> cos, kc=2j+1 -> +sin                (inv-W, B side)
// Ebf[h][ir]  (256x64): ir=2i -> cos, ir=2i+1 -> -sin                (inv-H, A side)
// Wt[o,c,i,j] = sum_r proj[o,r] * (cr + i*ci)[r,c,i,j]
__global__ void kSetup(const float* __restrict__ proj, const float* __restrict__ cr,
                       const float* __restrict__ ci, ushort* __restrict__ Dbf,
                       ushort* __restrict__ Gbf, ushort* __restrict__ Ebf,
                       float2* __restrict__ Wt) {
    int blk = blockIdx.x, tid = threadIdx.x;
    if (blk < 64) {
        float s, c;
        int jr = blk, w = tid;
        __sincosf((((jr >> 1) * w) & 255) * THETA, &s, &c);
        Dbf[jr * 256 + w] = (jr & 1) ? f2bf(-s) : f2bf(c);
        Gbf[w * 64 + jr]  = (jr & 1) ? f2bf(s)  : f2bf(c);
        return;
    }
    if (blk < 128) {
        float s, c;
        int e = (blk - 64) * 256 + tid;
        int h = e >> 6, ir = e & 63;
        __sincosf((((ir >> 1) * h) & 255) * THETA, &s, &c);
        Ebf[h * 64 + ir] = (ir & 1) ? f2bf(-s) : f2bf(c);
        return;
    }
    __shared__ float2 co[32][33];
    __shared__ float pr[32 * 32];
    int bb = blk - 128;
    int c = bb >> 5;
    int i = bb & 31;
    for (int idx = tid; idx < 1024; idx += 256) pr[idx] = proj[idx];
    for (int idx = tid; idx < 1024; idx += 256) {
        int r = idx >> 5, j = idx & 31;
        int g = ((r * 32 + c) * 32 + i) * 32 + j;
        co[r][j] = make_float2(cr[g], ci[g]);
    }
    __syncthreads();
    int j = tid & 31, og = tid >> 5;
    for (int oo = 0; oo < 4; ++oo) {
        int o = og * 4 + oo;
        float wr = 0.f, wi = 0.f;
        #pragma unroll
        for (int r = 0; r < 32; ++r) {
            float p = pr[o * 32 + r];
            float2 v = co[r][j];
            wr += p * v.x;
            wi += p * v.y;
        }
        Wt[((o * 32 + c) * 32 + i) * 32 + j] = make_float2(wr, wi);
    }
}

// ---- kA (fused k1+k2): per (b,c): x -> [W-DFT MFMA] -> Y1(LDS) -> [H-DFT MFMA]
//      -> combine -> Xf[b,c,i,j]
__global__ void __launch_bounds__(256) kA(const float* __restrict__ x,
                                          const ushort* __restrict__ Dbf,
                                          float2* __restrict__ Xf) {
    __shared__ __align__(16) ushort Xl[128 * 136];  // 34.8 KB x tile; aliased Ol f32[64*68]
    __shared__ __align__(16) ushort Yl[64 * 264];   // 33.8 KB Y1 rows [Yr j | Yi j] x 256 h
    int bc = blockIdx.x;
    int tid = threadIdx.x;
    int l = tid & 63, wv = tid >> 6;
    int lr = l & 15, kg = l >> 4;

    const float4* xp4 = (const float4*)(x + (size_t)bc * 65536);

    for (int hh = 0; hh < 2; ++hh) {
        f32x4 acc1[4][2];
        #pragma unroll
        for (int mt = 0; mt < 4; ++mt)
            #pragma unroll
            for (int nt = 0; nt < 2; ++nt)
                acc1[mt][nt] = (f32x4){0.f, 0.f, 0.f, 0.f};
        for (int wh = 0; wh < 2; ++wh) {
            __syncthreads();           // Xl free (prev MFMA1 readers done)
            #pragma unroll
            for (int k = 0; k < 16; ++k) {
                int idx = tid + 256 * k;
                int row = idx >> 5, wl4 = idx & 31;
                float4 v = xp4[(hh * 128 + row) * 64 + wh * 32 + wl4];
                ushort4 u = make_ushort4(f2bf(v.x), f2bf(v.y), f2bf(v.z), f2bf(v.w));
                *(ushort4*)&Xl[row * 136 + wl4 * 4] = u;
            }
            __syncthreads();
            #pragma unroll
            for (int ks = 0; ks < 4; ++ks) {
                bf16x8 a[4], b[2];
                #pragma unroll
                for (int mt = 0; mt < 4; ++mt)
                    a[mt] = *(const bf16x8*)&Dbf[(mt * 16 + lr) * 256 + wh * 128 + ks * 32 + kg * 8];
                #pragma unroll
                for (int nt = 0; nt < 2; ++nt)
                    b[nt] = *(const bf16x8*)&Xl[((wv * 2 + nt) * 16 + lr) * 136 + ks * 32 + kg * 8];
                #pragma unroll
                for (int mt = 0; mt < 4; ++mt)
                    #pragma unroll
                    for (int nt = 0; nt < 2; ++nt)
                        acc1[mt][nt] = __builtin_amdgcn_mfma_f32_16x16x32_bf16(
                            a[mt], b[nt], acc1[mt][nt], 0, 0, 0);
            }
        }
        // Y1 -> LDS, row-permuted for MFMA2's B operand: row = (im?32:0) + j
        #pragma unroll
        for (int mt = 0; mt < 4; ++mt)
            #pragma unroll
            for (int nt = 0; nt < 2; ++nt)
                #pragma unroll
                for (int r = 0; r < 4; ++r) {
                    int jr = mt * 16 + kg * 4 + r;
                    int row = ((jr & 1) << 5) | (jr >> 1);
                    int h = hh * 128 + (wv * 2 + nt) * 16 + lr;
                    Yl[row * 264 + h] = f2bf(acc1[mt][nt][r]);
                }
    }
    __syncthreads();                  // all Yl written
    // MFMA2: P = Dbf(64 ir x 256 h) x Yl(64 rows x 256 h)
    f32x4 acc2[4];
    #pragma unroll
    for (int mt = 0; mt < 4; ++mt) acc2[mt] = (f32x4){0.f, 0.f, 0.f, 0.f};
    #pragma unroll
    for (int ks = 0; ks < 8; ++ks) {
        bf16x8 a[4], b;
        #pragma unroll
        for (int mt = 0; mt < 4; ++mt)
            a[mt] = *(const bf16x8*)&Dbf[(mt * 16 + lr) * 256 + ks * 32 + kg * 8];
        b = *(const bf16x8*)&Yl[(wv * 16 + lr) * 264 + ks * 32 + kg * 8];
        #pragma unroll
        for (int mt = 0; mt < 4; ++mt)
            acc2[mt] = __builtin_amdgcn_mfma_f32_16x16x32_bf16(a[mt], b, acc2[mt], 0, 0, 0);
    }
    // combine via Ol (aliases Xl; Xl's last readers pre-date the barrier above)
    float* Ol = (float*)Xl;           // [64 m][68 stride]
    #pragma unroll
    for (int mt = 0; mt < 4; ++mt)
        #pragma unroll
        for (int r = 0; r < 4; ++r)
            Ol[(mt * 16 + kg * 4 + r) * 68 + wv * 16 + lr] = acc2[mt][r];
    __syncthreads();
    // Xr = P[2i][j] - P[2i+1][32+j]; Xi = P[2i][32+j] + P[2i+1][j]
    #pragma unroll
    for (int q = 0; q < 4; ++q) {
        int idx = tid + 256 * q;
        int i = idx >> 5, j = idx & 31;
        float Xr = Ol[(2 * i) * 68 + j] - Ol[(2 * i + 1) * 68 + 32 + j];
        float Xi = Ol[(2 * i) * 68 + 32 + j] + Ol[(2 * i + 1) * 68 + j];
        Xf[(size_t)bc * 1024 + i * 32 + j] = make_float2(Xr, Xi);
    }
}

// ---- K3: Of[b,o,i,j] = sum_c Xf[b,c,i,j] * Wt[o,c,i,j] ----------------------
__global__ void k3(const float2* __restrict__ Xf, const float2* __restrict__ Wt,
                   float2* __restrict__ Of) {
    __shared__ float2 xs[32][33];  // [c][j]
    int bid = blockIdx.x;          // b*32 + i
    int i = bid & 31, b = bid >> 5;
    int tid = threadIdx.x;
    for (int idx = tid; idx < 1024; idx += 256) {
        int c = idx >> 5, j = idx & 31;
        xs[c][j] = Xf[((b * 32 + c) * 32 + i) * 32 + j];
    }
    __syncthreads();
    int j = tid & 31, og = tid >> 5;
    for (int oo = 0; oo < 4; ++oo) {
        int o = og * 4 + oo;
        float orr = 0.f, oi = 0.f;
        for (int c = 0; c < 32; ++c) {
            float2 xv = xs[c][j];
            float2 wv = Wt[((o * 32 + c) * 32 + i) * 32 + j];
            orr += xv.x * wv.x - xv.y * wv.y;
            oi  += xv.x * wv.y + xv.y * wv.x;
        }
        Of[((b * 32 + o) * 32 + i) * 32 + j] = make_float2(orr, oi);
    }
}

// ---- kB (fused k4+k5): per (b,o): Of -> [inv-W MFMA] -> T2(LDS) ->
//      [inv-H MFMA] -> out[b,o,:,:]
__global__ void __launch_bounds__(256) kB(const float2* __restrict__ Of,
                                          const ushort* __restrict__ Gbf,
                                          const ushort* __restrict__ Ebf,
                                          float* __restrict__ out) {
    __shared__ __align__(16) ushort Al[64 * 72];    // 9.2 KB
    __shared__ __align__(16) ushort Tl[256 * 72];   // 36.9 KB, [w][kr]
    int bo = blockIdx.x;
    int tid = threadIdx.x;
    int l = tid & 63, wv = tid >> 6;
    int lr = l & 15, kg = l >> 4;
    // A = interleaved [cj*Or, -cj*Oi; cj*Oi, cj*Or] / 65536
    #pragma unroll
    for (int q = 0; q < 4; ++q) {
        int idx = tid + 256 * q;
        int i = idx >> 5, j = idx & 31;
        float2 v = Of[(size_t)bo * 1024 + idx];
        float sc = (j ? 2.0f : 1.0f) * (1.0f / 65536.0f);
        Al[(2 * i) * 72 + 2 * j]         = f2bf(sc * v.x);
        Al[(2 * i) * 72 + 2 * j + 1]     = f2bf(-sc * v.y);
        Al[(2 * i + 1) * 72 + 2 * j]     = f2bf(sc * v.y);
        Al[(2 * i + 1) * 72 + 2 * j + 1] = f2bf(sc * v.x);
    }
    __syncthreads();
    {   // MFMA1: T2[kr 64][w 256] = Al x Gbf; each wave covers 64 w
        f32x4 acc[4][4];
        #pragma unroll
        for (int mt = 0; mt < 4; ++mt)
            #pragma unroll
            for (int nt = 0; nt < 4; ++nt)
                acc[mt][nt] = (f32x4){0.f, 0.f, 0.f, 0.f};
        #pragma unroll
        for (int ks = 0; ks < 2; ++ks) {
            bf16x8 a[4], b[4];
            #pragma unroll
            for (int mt = 0; mt < 4; ++mt)
                a[mt] = *(const bf16x8*)&Al[(mt * 16 + lr) * 72 + ks * 32 + kg * 8];
            #pragma unroll
            for (int nt = 0; nt < 4; ++nt)
                b[nt] = *(const bf16x8*)&Gbf[(wv * 64 + nt * 16 + lr) * 64 + ks * 32 + kg * 8];
            #pragma unroll
            for (int mt = 0; mt < 4; ++mt)
                #pragma unroll
                for (int nt = 0; nt < 4; ++nt)
                    acc[mt][nt] = __builtin_amdgcn_mfma_f32_16x16x32_bf16(
                        a[mt], b[nt], acc[mt][nt], 0, 0, 0);
        }
        // write T2 to LDS transposed: Tl[w][kr], 8B per (mt,nt)
        #pragma unroll
        for (int mt = 0; mt < 4; ++mt) {
            int kr0 = mt * 16 + kg * 4;
            #pragma unroll
            for (int nt = 0; nt < 4; ++nt) {
                int w = wv * 64 + nt * 16 + lr;
                ushort4 u = make_ushort4(f2bf(acc[mt][nt][0]), f2bf(acc[mt][nt][1]),
                                         f2bf(acc[mt][nt][2]), f2bf(acc[mt][nt][3]));
                *(ushort4*)&Tl[w * 72 + kr0] = u;
            }
        }
    }
    __syncthreads();
    // MFMA2: out[h,w] = Ebf(256h x 64kr) x Tl(w x kr); wave wv covers h in
    // [wv*64, wv*64+64); w processed in 4 chunks of 64.
    float* op = out + (size_t)bo * 65536;
    for (int nc = 0; nc < 4; ++nc) {
        f32x4 acc[4][4];
        #pragma unroll
        for (int mm = 0; mm < 4; ++mm)
            #pragma unroll
            for (int nt = 0; nt < 4; ++nt)
                acc[mm][nt] = (f32x4){0.f, 0.f, 0.f, 0.f};
        #pragma unroll
        for (int ks = 0; ks < 2; ++ks) {
            bf16x8 a[4], b[4];
            #pragma unroll
            for (int mm = 0; mm < 4; ++mm)
                a[mm] = *(const bf16x8*)&Ebf[((wv * 4 + mm) * 16 + lr) * 64 + ks * 32 + kg * 8];
            #pragma unroll
            for (int nt = 0; nt < 4; ++nt)
                b[nt] = *(const bf16x8*)&Tl[(nc * 64 + nt * 16 + lr) * 72 + ks * 32 + kg * 8];
            #pragma unroll
            for (int mm = 0; mm < 4; ++mm)
                #pragma unroll
                for (int nt = 0; nt < 4; ++nt)
                    acc[mm][nt] = __builtin_amdgcn_mfma_f32_16x16x32_bf16(
                        a[mm], b[nt], acc[mm][nt], 0, 0, 0);
        }
        #pragma unroll
        for (int mm = 0; mm < 4; ++mm)
            #pragma unroll
            for (int nt = 0; nt < 4; ++nt)
                #pragma unroll
                for (int r = 0; r < 4; ++r) {
                    int h = (wv * 4 + mm) * 16 + kg * 4 + r;
                    int w = nc * 64 + nt * 16 + lr;
                    op[h * 256 + w] = acc[mm][nt][r];
                }
    }
}

extern "C" void kernel_launch(void* const* d_in, const int* in_sizes, int n_in,
                              void* d_out, int out_size, void* d_ws, size_t ws_size,
                              hipStream_t stream) {
    const float* x    = (const float*)d_in[0];
    const float* cr   = (const float*)d_in[1];
    const float* ci   = (const float*)d_in[2];
    const float* proj = (const float*)d_in[3];
    float* out = (float*)d_out;
    char* ws = (char*)d_ws;

    // ws layout (16,875,520 B used):
    //   Xf  @ 0         4,194,304  (float2)
    //   Wt  @ 4MiB      8,388,608  (float2)
    //   Of  @ 12MiB     4,194,304  (float2)
    //   Dbf @ 16MiB        32,768  (bf16 64x256)
    //   Gbf @ +32KB        32,768  (bf16 256x64)
    //   Ebf @ +64KB        32,768  (bf16 256x64)
    float2* Xf  = (float2*)ws;
    float2* Wt  = (float2*)(ws + 4194304);
    float2* Of  = (float2*)(ws + 12582912);
    ushort* Dbf = (ushort*)(ws + 16777216);
    ushort* Gbf = (ushort*)(ws + 16777216 + 32768);
    ushort* Ebf = (ushort*)(ws + 16777216 + 65536);

    kSetup<<<1152, 256, 0, stream>>>(proj, cr, ci, Dbf, Gbf, Ebf, Wt);
    kA<<<512, 256, 0, stream>>>(x, Dbf, Xf);
    k3<<<512, 256, 0, stream>>>(Xf, Wt, Of);
    kB<<<512, 256, 0, stream>>>(Of, Gbf, Ebf, out);
}